// Round 13
// baseline (232.467 us; speedup 1.0000x reference)
//
#include <hip/hip_runtime.h>
#include <hip/hip_bf16.h>
#include <math.h>

typedef __hip_bfloat16 bf16;
typedef __attribute__((ext_vector_type(4))) float f32x4;
typedef __attribute__((ext_vector_type(8))) short s16x8;

#define T_SEQ 2048
#define DIM   2048
#define NH    16
#define LAT   512
#define RD    64
#define TOPK  32

typedef const __attribute__((address_space(1))) void* gas_ptr;
typedef __attribute__((address_space(3))) void* las_ptr;

// ---------------------------------------------------------------------------
// Grouped GEMM descriptors.
// flags: 1 = RoPE epilogue (rotate col pairs (c, c+32), position = t0+row),
//        2 = column guard (col < N; B-staging rows clamped to N-1),
//        4 = fp32 output (C reinterpreted float*).
// ---------------------------------------------------------------------------
struct GGroup {
    const bf16* A; const bf16* BT; bf16* C;
    int K, lda, ldb, ldc;
    int tx, ty, nz;          // tiles in n, m, z
    long aZ, bZ, cZ;         // element strides per z
    int tiles;               // tx*ty*nz
    int flags, N, t0;
};
struct GPack { GGroup g[4]; int n; };

// ---------------------------------------------------------------------------
// MT x 64-tile grouped GEMM, BK=64. Grid policy (r16/r17 PMC): grid >= 2
// blocks/CU dominates all other levers. DB=1 (r20): 2-phase dbuf.
// r22 lesson: with grid >= 2/CU, single-K + DB beats split-K + reduce
// (the partial round-trip + launch costs more than K-halving saves).
// ---------------------------------------------------------------------------
template<int MT, int DB>
__global__ __launch_bounds__(256)
void gemm_group(GPack gp)
{
    constexpr int MI = MT / 64;          // i-frags per wave (1 or 2)

    int b = blockIdx.x;
    int gi = 0;
    while (gi < gp.n - 1 && b >= gp.g[gi].tiles) { b -= gp.g[gi].tiles; ++gi; }
    const GGroup g = gp.g[gi];

    // T1: bijective XCD swizzle (m204).
    {
        const int nwg = g.tiles;
        const int xcd = b & 7, idx = b >> 3;
        const int qq = nwg >> 3, rr = nwg & 7;
        b = (xcd < rr ? xcd * (qq + 1) : rr * (qq + 1) + (xcd - rr) * qq) + idx;
    }

    const int per_z = g.tx * g.ty;
    const int z   = b / per_z;
    const int rem = b - z * per_z;
    const int bx  = rem % g.tx;
    const int by  = rem / g.tx;

    const bf16* A  = g.A  + (size_t)z * g.aZ;
    const bf16* BT = g.BT + (size_t)z * g.bZ;
    bf16*       C  = g.C  + (size_t)z * g.cZ;

    __shared__ bf16 aL[(DB + 1) * MT * 64];
    __shared__ bf16 bL[(DB + 1) * 64 * 64];

    const int tid  = threadIdx.x;
    const int wave = tid >> 6;
    const int lane = tid & 63;
    const int quad = lane >> 4;
    const int l16  = lane & 15;

    const int tile_m = by * MT;
    const int tile_n = bx * 64;
    const int wrow = wave * (MT / 4);

    const int lrow = lane >> 3;
    const int lke  = (((lane & 7) ^ lrow) * 8);      // XOR-swizzled seg
    const int sw   = l16 & 7;

    f32x4 acc[MI][4] = {};

    const int nt = g.K >> 6;

    auto stage = [&](int t, int sb) {
        const int k0 = t << 6;
#pragma unroll
        for (int p = 0; p < 2 * MI; ++p) {
            const int R = (wave * 2 * MI + p) * 8;
            const bf16* src = A + (size_t)(tile_m + R + lrow) * g.lda + k0 + lke;
            __builtin_amdgcn_global_load_lds((gas_ptr)src,
                (las_ptr)(aL + sb * MT * 64 + R * 64), 16, 0, 0);
        }
#pragma unroll
        for (int p = 0; p < 2; ++p) {
            const int R = (wave * 2 + p) * 8;
            int brow = tile_n + R + lrow;
            if (g.flags & 2) brow = brow < g.N ? brow : g.N - 1;
            const bf16* src = BT + (size_t)brow * g.ldb + k0 + lke;
            __builtin_amdgcn_global_load_lds((gas_ptr)src,
                (las_ptr)(bL + sb * 4096 + R * 64), 16, 0, 0);
        }
    };

    auto compute = [&](int sb) {
#pragma unroll
        for (int ks = 0; ks < 2; ++ks) {
            s16x8 af[MI], bfr[4];
#pragma unroll
            for (int i = 0; i < MI; ++i)
                af[i] = *(const s16x8*)(&aL[sb * MT * 64 + (wrow + i * 16 + l16) * 64 +
                                            (((ks * 4 + quad) ^ sw) * 8)]);
#pragma unroll
            for (int j = 0; j < 4; ++j)
                bfr[j] = *(const s16x8*)(&bL[sb * 4096 + (j * 16 + l16) * 64 +
                                             (((ks * 4 + quad) ^ sw) * 8)]);

#pragma unroll
            for (int i = 0; i < MI; ++i)
#pragma unroll
                for (int j = 0; j < 4; ++j)
                    acc[i][j] = __builtin_amdgcn_mfma_f32_16x16x32_bf16(
                        af[i], bfr[j], acc[i][j], 0, 0, 0);
        }
    };

    if (DB) {
        stage(0, 0);
        asm volatile("s_waitcnt vmcnt(0)" ::: "memory");
        __builtin_amdgcn_s_barrier();
        int cur = 0;
        for (int t = 0; t < nt; ++t) {
            if (t + 1 < nt) stage(t + 1, cur ^ 1);   // loads fly under compute
            compute(cur);
            asm volatile("s_waitcnt vmcnt(0)" ::: "memory");
            __builtin_amdgcn_s_barrier();
            cur ^= 1;
        }
    } else {
        for (int t = 0; t < nt; ++t) {
            stage(t, 0);
            __syncthreads();
            compute(0);
            __syncthreads();
        }
    }

    // D mapping: col = lane&15, row = (lane>>4)*4 + reg   [m89-verified]
    if (g.flags & 1) {
#pragma unroll
        for (int jp = 0; jp < 2; ++jp) {
            const int colL = tile_n + jp * 16 + l16;
            if ((g.flags & 2) && colL >= g.N) continue;
            const float fr = powf(10000.f, -(float)(jp * 16 + l16) / 32.f);
#pragma unroll
            for (int i = 0; i < MI; ++i) {
#pragma unroll
                for (int r = 0; r < 4; ++r) {
                    const int row = tile_m + wrow + i * 16 + quad * 4 + r;
                    float sv, cv;
                    sincosf((float)(g.t0 + row) * fr, &sv, &cv);
                    const float x0 = acc[i][jp][r];
                    const float x1 = acc[i][jp + 2][r];
                    C[(size_t)row * g.ldc + colL]      = __float2bfloat16(x0 * cv - x1 * sv);
                    C[(size_t)row * g.ldc + colL + 32] = __float2bfloat16(x1 * cv + x0 * sv);
                }
            }
        }
    } else if (g.flags & 4) {
        float* Cf = (float*)C;
#pragma unroll
        for (int j = 0; j < 4; ++j) {
            const int col = tile_n + j * 16 + l16;
#pragma unroll
            for (int i = 0; i < MI; ++i)
#pragma unroll
                for (int r = 0; r < 4; ++r) {
                    const int row = tile_m + wrow + i * 16 + quad * 4 + r;
                    Cf[(size_t)row * g.ldc + col] = acc[i][j][r];
                }
        }
    } else {
#pragma unroll
        for (int j = 0; j < 4; ++j) {
            const int col = tile_n + j * 16 + l16;
            if ((g.flags & 2) && col >= g.N) continue;
#pragma unroll
            for (int i = 0; i < MI; ++i)
#pragma unroll
                for (int r = 0; r < 4; ++r) {
                    const int row = tile_m + wrow + i * 16 + quad * 4 + r;
                    C[(size_t)row * g.ldc + col] = __float2bfloat16(acc[i][j][r]);
                }
        }
    }
}

// ---------------------------------------------------------------------------
// 128x128-tile grouped GEMM: 4 waves 2x2, 64x64/wave, acc[4][4].
// DB=1: same 2-phase dbuf. Use when grid >= 2/CU.
// ---------------------------------------------------------------------------
template<int DB>
__global__ __launch_bounds__(256)
void gemm128(GPack gp)
{
    int b = blockIdx.x;
    int gi = 0;
    while (gi < gp.n - 1 && b >= gp.g[gi].tiles) { b -= gp.g[gi].tiles; ++gi; }
    const GGroup g = gp.g[gi];

    {
        const int nwg = g.tiles;
        const int xcd = b & 7, idx = b >> 3;
        const int qq = nwg >> 3, rr = nwg & 7;
        b = (xcd < rr ? xcd * (qq + 1) : rr * (qq + 1) + (xcd - rr) * qq) + idx;
    }

    const int per_z = g.tx * g.ty;
    const int z   = b / per_z;
    const int rem = b - z * per_z;
    const int bx  = rem % g.tx;
    const int by  = rem / g.tx;

    const bf16* A  = g.A  + (size_t)z * g.aZ;
    const bf16* BT = g.BT + (size_t)z * g.bZ;
    bf16*       C  = g.C  + (size_t)z * g.cZ;

    __shared__ bf16 aL[(DB + 1) * 128 * 64];
    __shared__ bf16 bL[(DB + 1) * 128 * 64];

    const int tid  = threadIdx.x;
    const int wave = tid >> 6;
    const int lane = tid & 63;
    const int quad = lane >> 4;
    const int l16  = lane & 15;

    const int tile_m = by * 128;
    const int tile_n = bx * 128;
    const int wm = (wave >> 1) * 64;
    const int wn = (wave & 1) * 64;

    const int lrow = lane >> 3;
    const int lke  = (((lane & 7) ^ lrow) * 8);
    const int sw   = l16 & 7;

    f32x4 acc[4][4] = {};

    const int nt = g.K >> 6;

    auto stage = [&](int t, int sb) {
        const int k0 = t << 6;
#pragma unroll
        for (int p = 0; p < 4; ++p) {
            const int R = (wave * 4 + p) * 8;
            const bf16* srcA = A + (size_t)(tile_m + R + lrow) * g.lda + k0 + lke;
            __builtin_amdgcn_global_load_lds((gas_ptr)srcA,
                (las_ptr)(aL + sb * 8192 + R * 64), 16, 0, 0);
            int brow = tile_n + R + lrow;
            if (g.flags & 2) brow = brow < g.N ? brow : g.N - 1;
            const bf16* srcB = BT + (size_t)brow * g.ldb + k0 + lke;
            __builtin_amdgcn_global_load_lds((gas_ptr)srcB,
                (las_ptr)(bL + sb * 8192 + R * 64), 16, 0, 0);
        }
    };

    auto compute = [&](int sb) {
#pragma unroll
        for (int ks = 0; ks < 2; ++ks) {
            const int seg = ((ks * 4 + quad) ^ sw) * 8;
            s16x8 af[4], bf_[4];
#pragma unroll
            for (int i = 0; i < 4; ++i)
                af[i] = *(const s16x8*)(&aL[sb * 8192 + (wm + i * 16 + l16) * 64 + seg]);
#pragma unroll
            for (int j = 0; j < 4; ++j)
                bf_[j] = *(const s16x8*)(&bL[sb * 8192 + (wn + j * 16 + l16) * 64 + seg]);

#pragma unroll
            for (int i = 0; i < 4; ++i)
#pragma unroll
                for (int j = 0; j < 4; ++j)
                    acc[i][j] = __builtin_amdgcn_mfma_f32_16x16x32_bf16(
                        af[i], bf_[j], acc[i][j], 0, 0, 0);
        }
    };

    if (DB) {
        stage(0, 0);
        asm volatile("s_waitcnt vmcnt(0)" ::: "memory");
        __builtin_amdgcn_s_barrier();
        int cur = 0;
        for (int t = 0; t < nt; ++t) {
            if (t + 1 < nt) stage(t + 1, cur ^ 1);
            compute(cur);
            asm volatile("s_waitcnt vmcnt(0)" ::: "memory");
            __builtin_amdgcn_s_barrier();
            cur ^= 1;
        }
    } else {
        for (int t = 0; t < nt; ++t) {
            stage(t, 0);
            __syncthreads();
            compute(0);
            __syncthreads();
        }
    }

    if (g.flags & 1) {
#pragma unroll
        for (int jp = 0; jp < 2; ++jp) {
            const int colL = tile_n + wn + jp * 16 + l16;
            if ((g.flags & 2) && colL >= g.N) continue;
            const float fr = powf(10000.f, -(float)(jp * 16 + l16) / 32.f);
#pragma unroll
            for (int i = 0; i < 4; ++i) {
#pragma unroll
                for (int r = 0; r < 4; ++r) {
                    const int row = tile_m + wm + i * 16 + quad * 4 + r;
                    float sv, cv;
                    sincosf((float)(g.t0 + row) * fr, &sv, &cv);
                    const float x0 = acc[i][jp][r];
                    const float x1 = acc[i][jp + 2][r];
                    C[(size_t)row * g.ldc + colL]      = __float2bfloat16(x0 * cv - x1 * sv);
                    C[(size_t)row * g.ldc + colL + 32] = __float2bfloat16(x1 * cv + x0 * sv);
                }
            }
        }
    } else if (g.flags & 4) {
        float* Cf = (float*)C;
#pragma unroll
        for (int j = 0; j < 4; ++j) {
            const int col = tile_n + wn + j * 16 + l16;
#pragma unroll
            for (int i = 0; i < 4; ++i)
#pragma unroll
                for (int r = 0; r < 4; ++r) {
                    const int row = tile_m + wm + i * 16 + quad * 4 + r;
                    Cf[(size_t)row * g.ldc + col] = acc[i][j][r];
                }
        }
    } else {
#pragma unroll
        for (int j = 0; j < 4; ++j) {
            const int col = tile_n + wn + j * 16 + l16;
            if ((g.flags & 2) && col >= g.N) continue;
#pragma unroll
            for (int i = 0; i < 4; ++i)
#pragma unroll
                for (int r = 0; r < 4; ++r) {
                    const int row = tile_m + wm + i * 16 + quad * 4 + r;
                    C[(size_t)row * g.ldc + col] = __float2bfloat16(acc[i][j][r]);
                }
        }
    }
}

// ---------------------------------------------------------------------------
// Batched transpose+convert: fp32 (R x C) -> bf16 (C x R), 32x32 LDS tiles.
// ---------------------------------------------------------------------------
struct TDesc { const float* src; bf16* dst; int R; int C; int tiles; int ctiles; };
struct TPack { TDesc d[8]; int n; };

__global__ __launch_bounds__(256)
void transpose_batch(TPack p)
{
    int b = blockIdx.x;
    int mi = 0;
    while (mi < p.n - 1 && b >= p.d[mi].tiles) { b -= p.d[mi].tiles; ++mi; }
    const TDesc d = p.d[mi];
    const int tr = b / d.ctiles, tc = b % d.ctiles;
    const int r0 = tr * 32, c0 = tc * 32;

    __shared__ float lds[32][33];
    const int tx = threadIdx.x & 31, ty = threadIdx.x >> 5;
#pragma unroll
    for (int i = 0; i < 4; ++i)
        lds[ty * 4 + i][tx] = d.src[(size_t)(r0 + ty * 4 + i) * d.C + c0 + tx];
    __syncthreads();
#pragma unroll
    for (int i = 0; i < 4; ++i)
        d.dst[(size_t)(c0 + ty * 4 + i) * d.R + r0 + tx] =
            __float2bfloat16(lds[tx][ty * 4 + i]);
}

// ---------------------------------------------------------------------------
// r21: fused Phase A — converts (block range [0, cblocks)) + transposes
// (rest). One launch instead of two (launch count is first-order).
// ---------------------------------------------------------------------------
struct APack {
    const float* s0; bf16* d0; int n0;
    const float* s1; bf16* d1; int n1;
    int cblocks;
    TPack tp;
};

__global__ __launch_bounds__(256)
void phaseA(APack p)
{
    __shared__ float lds[32][33];
    if ((int)blockIdx.x < p.cblocks) {
        int i = blockIdx.x * blockDim.x + threadIdx.x;   // 8-elem units
        const float* s; bf16* d;
        if (i < p.n0) { s = p.s0; d = p.d0; }
        else if (i < p.n0 + p.n1) { i -= p.n0; s = p.s1; d = p.d1; }
        else return;
        const float4 a = *(const float4*)(s + (size_t)i * 8);
        const float4 b = *(const float4*)(s + (size_t)i * 8 + 4);
        bf16 t[8];
        t[0] = __float2bfloat16(a.x); t[1] = __float2bfloat16(a.y);
        t[2] = __float2bfloat16(a.z); t[3] = __float2bfloat16(a.w);
        t[4] = __float2bfloat16(b.x); t[5] = __float2bfloat16(b.y);
        t[6] = __float2bfloat16(b.z); t[7] = __float2bfloat16(b.w);
        *(uint4*)(d + (size_t)i * 8) = *(uint4*)t;
        return;
    }
    int b = blockIdx.x - p.cblocks;
    int mi = 0;
    while (mi < p.tp.n - 1 && b >= p.tp.d[mi].tiles) { b -= p.tp.d[mi].tiles; ++mi; }
    const TDesc d = p.tp.d[mi];
    const int tr = b / d.ctiles, tc = b % d.ctiles;
    const int r0 = tr * 32, c0 = tc * 32;
    const int tx = threadIdx.x & 31, ty = threadIdx.x >> 5;
#pragma unroll
    for (int i = 0; i < 4; ++i)
        lds[ty * 4 + i][tx] = d.src[(size_t)(r0 + ty * 4 + i) * d.C + c0 + tx];
    __syncthreads();
#pragma unroll
    for (int i = 0; i < 4; ++i)
        d.dst[(size_t)(c0 + ty * 4 + i) * d.R + r0 + tx] =
            __float2bfloat16(lds[tx][ty * 4 + i]);
}

// ---------------------------------------------------------------------------
// MLA-absorbed sparse attention. One block per query t.
// r17: QK^T wave-K-split + cross-wave LDS reduction.
// r21: ckv quad-XOR seg swizzle (global-side stage permute, readers un-XOR).
// r23: coalesced U store. Old epilogue: 32 scalar 2B stores/lane at
// (head*512+col) -> four 32B half-line chunks 1KB apart per instr (U = 32MB
// of writes at ~half line utilization). New: PV accumulates into regs
// (static-indexed uacc), then round-trips a 16KB LDS buffer overlaid on the
// dead kr/qr/P/red union (one barrier guards the overlay), stored as 1024
// contiguous uint4 -> fully coalesced 64B groups. LDS total unchanged.
// ---------------------------------------------------------------------------
__global__ __launch_bounds__(256)
void attn_mla(const bf16* __restrict__ qt,   // [rows][8192] chunk (q~ per head)
              const bf16* __restrict__ qr,   // [rows][1024] chunk (rope'd)
              const bf16* __restrict__ xw,   // [2048][1024], ckv = cols 512..1023
              const bf16* __restrict__ kr,   // [2048][64] (rope'd)
              const int*  __restrict__ topk, // [2048][32]
              bf16* __restrict__ U,          // [rows][8192]
              int t0)
{
    __shared__ short ckv_s[32 * 520];
    __shared__ uint4 uni4[1024];             // 16 KB union (kr|qr|P|red -> ubuf)
    __shared__ int   idx_s[32];

    short* kr_s = (short*)uni4;                    // [32*72]  = 4608 B @ 0
    short* qr_s = (short*)((char*)uni4 + 4608);    // [16*72]  = 2304 B @ 4608
    short* P_sb = (short*)((char*)uni4 + 6912);    // [4][640] = 5120 B @ 6912
    float* redb = (float*)((char*)uni4 + 12032);   // [4][64][4] = 4096 B @ 12032

    const int tl   = blockIdx.x;
    const int tg   = t0 + tl;
    const int tid  = threadIdx.x;
    const int wv   = tid >> 6;
    const int lane = tid & 63;
    const int quad = lane >> 4;
    const int l16  = lane & 15;

    if (tid < 32) {
        int j = topk[(size_t)tg * TOPK + tid];
        idx_s[tid] = (j < 0 || j >= T_SEQ) ? 0 : j;
    }
    __syncthreads();

    // Stage ckv rows with seg-XOR on the GLOBAL side (dest linear):
    // LDS[row][seg s] = global seg (s ^ (row>>3)); row>>3 == wv here.
#pragma unroll
    for (int i = 0; i < 8; ++i) {
        const int row = wv * 8 + i;
        const int j = idx_s[row];
        __builtin_amdgcn_global_load_lds(
            (gas_ptr)(xw + (size_t)j * 1024 + 512 + ((lane ^ wv) * 8)),
            (las_ptr)(ckv_s + row * 520), 16, 0, 0);
    }
    {
        const int row = tid >> 3, seg = tid & 7;
        const int j = idx_s[row];
        *(uint4*)(kr_s + row * 72 + seg * 8) =
            *(const uint4*)(kr + (size_t)j * RD + seg * 8);
    }
    if (tid < 128) {
        const int head = tid >> 3, seg = tid & 7;
        *(uint4*)(qr_s + head * 72 + seg * 8) =
            *(const uint4*)(qr + (size_t)tl * 1024 + head * 64 + seg * 8);
    }
    __syncthreads();

    // QK^T partials: wave wv covers qt K-slices 4wv..4wv+3 (of 16).
    const bf16* qrow = qt + (size_t)tl * 8192 + l16 * 512;
    const int h0 = l16 >> 3;             // swz(row = l16); row 16+l16 -> 2+h0
    f32x4 sc[2] = {};
#pragma unroll
    for (int kk = 0; kk < 4; ++kk) {
        const int ks = wv * 4 + kk;
        s16x8 a  = *(const s16x8*)(qrow + ks * 32 + quad * 8);
        s16x8 b0 = *(const s16x8*)(ckv_s + l16 * 520 +
                                   (((ks * 4 + quad) ^ h0) * 8));
        s16x8 b1 = *(const s16x8*)(ckv_s + (16 + l16) * 520 +
                                   (((ks * 4 + quad) ^ (2 + h0)) * 8));
        sc[0] = __builtin_amdgcn_mfma_f32_16x16x32_bf16(a, b0, sc[0], 0, 0, 0);
        sc[1] = __builtin_amdgcn_mfma_f32_16x16x32_bf16(a, b1, sc[1], 0, 0, 0);
    }
    if (wv < 2) {   // rope contribution: K=64 -> 2 slices, one per wave 0/1
        const int ks = wv;
        s16x8 a  = *(const s16x8*)(qr_s + l16 * 72 + ks * 32 + quad * 8);
        s16x8 b0 = *(const s16x8*)(kr_s + l16 * 72 + ks * 32 + quad * 8);
        s16x8 b1 = *(const s16x8*)(kr_s + (16 + l16) * 72 + ks * 32 + quad * 8);
        sc[0] = __builtin_amdgcn_mfma_f32_16x16x32_bf16(a, b0, sc[0], 0, 0, 0);
        sc[1] = __builtin_amdgcn_mfma_f32_16x16x32_bf16(a, b1, sc[1], 0, 0, 0);
    }

    // Cross-wave reduction (2 passes through 4KB LDS).
    *(f32x4*)(redb + (wv * 64 + lane) * 4) = sc[0];
    __syncthreads();
    sc[0] = *(const f32x4*)(redb + (0 * 64 + lane) * 4) +
            *(const f32x4*)(redb + (1 * 64 + lane) * 4) +
            *(const f32x4*)(redb + (2 * 64 + lane) * 4) +
            *(const f32x4*)(redb + (3 * 64 + lane) * 4);
    __syncthreads();
    *(f32x4*)(redb + (wv * 64 + lane) * 4) = sc[1];
    __syncthreads();
    sc[1] = *(const f32x4*)(redb + (0 * 64 + lane) * 4) +
            *(const f32x4*)(redb + (1 * 64 + lane) * 4) +
            *(const f32x4*)(redb + (2 * 64 + lane) * 4) +
            *(const f32x4*)(redb + (3 * 64 + lane) * 4);

    const float scale = 0.0721687836487032f;   // 1/sqrt(192)
    float inv[4];
    short* pw = P_sb + wv * 640;
#pragma unroll
    for (int r = 0; r < 4; ++r) {
        float s0 = sc[0][r] * scale, s1 = sc[1][r] * scale;
        float mx = fmaxf(s0, s1);
#pragma unroll
        for (int off = 1; off < 16; off <<= 1) mx = fmaxf(mx, __shfl_xor(mx, off));
        float p0 = __expf(s0 - mx), p1 = __expf(s1 - mx);
        float l = p0 + p1;
#pragma unroll
        for (int off = 1; off < 16; off <<= 1) l += __shfl_xor(l, off);
        inv[r] = 1.f / l;
        pw[(quad * 4 + r) * 40 + l16]      = __builtin_bit_cast(short, __float2bfloat16(p0));
        pw[(quad * 4 + r) * 40 + 16 + l16] = __builtin_bit_cast(short, __float2bfloat16(p1));
    }

    s16x8 ap = *(const s16x8*)(pw + l16 * 40 + quad * 8);

    // PV into registers (static-indexed; rule #20).
    short uacc[8][4];
#pragma unroll
    for (int tt = 0; tt < 8; ++tt) {
        const int n0 = wv * 128 + tt * 16;
        const int cs = (n0 >> 3) + h0;          // global col seg of n0+l16
        s16x8 b;
#pragma unroll
        for (int j = 0; j < 8; ++j)
            b[j] = ckv_s[(quad * 8 + j) * 520 + ((cs ^ quad) << 3) + (l16 & 7)];
        f32x4 u = {};
        u = __builtin_amdgcn_mfma_f32_16x16x32_bf16(ap, b, u, 0, 0, 0);
#pragma unroll
        for (int r = 0; r < 4; ++r)
            uacc[tt][r] = __builtin_bit_cast(short, __float2bfloat16(u[r] * inv[r]));
    }

    // Overlay the (now dead) union with the 16KB U row block, then store
    // fully coalesced: 8192 bf16 = 1024 uint4 over 256 threads.
    __syncthreads();
    short* ub = (short*)uni4;            // [16 heads][512 cols]
#pragma unroll
    for (int tt = 0; tt < 8; ++tt)
#pragma unroll
        for (int r = 0; r < 4; ++r)
            ub[(quad * 4 + r) * 512 + wv * 128 + tt * 16 + l16] = uacc[tt][r];
    __syncthreads();
    {
        const uint4* s = (const uint4*)uni4;
        uint4* dU = (uint4*)(U + (size_t)tl * 8192);
#pragma unroll
        for (int k = 0; k < 4; ++k)
            dU[k * 256 + tid] = s[k * 256 + tid];
    }
}

// ---------------------------------------------------------------------------
extern "C" void kernel_launch(void* const* d_in, const int* in_sizes, int n_in,
                              void* d_out, int out_size, void* d_ws, size_t ws_size,
                              hipStream_t stream)
{
    const float* x    = (const float*)d_in[0];
    const float* Wqd  = (const float*)d_in[1];
    const float* Wqu  = (const float*)d_in[2];
    const float* Wqr  = (const float*)d_in[3];
    const float* Wkvd = (const float*)d_in[4];
    const float* Wku  = (const float*)d_in[5];
    const float* Wvu  = (const float*)d_in[6];
    const float* Wkr  = (const float*)d_in[7];
    const float* Wo   = (const float*)d_in[8];
    const int*   topk = (const int*)d_in[9];
    float* out = (float*)d_out;

    const size_t KB = 1024;
    char* ws = (char*)d_ws;
    const bool flat = ws_size >= (size_t)128000 * KB;
    const int  TCH  = flat ? 2048 : 512;
    const int  NCH  = T_SEQ / TCH;

    // q~ factorization (r10): q = ql@Wqu (ref-exact), q~_h = q_h@Wku_h^T
    // (rank-128 bottleneck) -> 8.6 GF vs 17.2+1.1 GF for the Wcomb path.
    size_t oXB, oWxT, oWkrT, oWquT, oWkub, oWqrT, oWvuT, oQ, oXW, oKR,
           oQR, oO, oWoT, oQT, oU;
    if (flat) {
        oXB = 0;       oWxT = 8192;   oWkrT = 12288; oWquT = 12544;
        oWkub = 14592; oWqrT = 16640; oWvuT = 17664; oQ = 19712;
        oXW = 27904;   oKR = 32000;   oQR = 32256;   oO = 36352;
        oWoT = 44544;  oQT = 52736;   oU = 85504;
    } else {
        // chunked (TCH=512), 38.3 MB peak; xb/WxT/WkrT die after phase B,
        // q aliases into dead-xb region, WoT over dead qt at the end.
        oXW = 0;       oKR = 4096;    oWquT = 4352;  oWkub = 6400;
        oWqrT = 8448;  oWvuT = 9472;  oO = 11520;    oXB = 19712;
        oWxT = 27904;  oWkrT = 32000; oQ = 19712;    oQT = 21760;
        oQR = 29952;   oU = 30976;    oWoT = 21760;
    }
    bf16* xb   = (bf16*)(ws + oXB * KB);
    bf16* WxT  = (bf16*)(ws + oWxT * KB);
    bf16* WkrT = (bf16*)(ws + oWkrT * KB);
    bf16* WquT = (bf16*)(ws + oWquT * KB);
    bf16* Wkub = (bf16*)(ws + oWkub * KB);
    bf16* WqrT = (bf16*)(ws + oWqrT * KB);
    bf16* WvuT = (bf16*)(ws + oWvuT * KB);
    bf16* qB   = (bf16*)(ws + oQ * KB);
    bf16* xw   = (bf16*)(ws + oXW * KB);
    bf16* kr   = (bf16*)(ws + oKR * KB);
    bf16* qrC  = (bf16*)(ws + oQR * KB);
    bf16* o    = (bf16*)(ws + oO * KB);
    bf16* WoT  = (bf16*)(ws + oWoT * KB);
    bf16* qtC  = (bf16*)(ws + oQT * KB);
    bf16* uC   = (bf16*)(ws + oU * KB);

    dim3 blk(256);

    // Phase A: fused convert (x, Wku) + transposes, single launch (r21).
    {
        int n0 = T_SEQ * DIM / 8, n1 = LAT * DIM / 8;
        APack ap;
        ap.s0 = x;   ap.d0 = xb;   ap.n0 = n0;
        ap.s1 = Wku; ap.d1 = Wkub; ap.n1 = n1;
        ap.cblocks = (n0 + n1 + 255) / 256;
        TPack& p = ap.tp;
        p.d[0] = { Wqd,  WxT,                   DIM, LAT,  (DIM/32)*(LAT/32),  LAT/32 };
        p.d[1] = { Wkvd, WxT + (size_t)LAT*DIM, DIM, LAT,  (DIM/32)*(LAT/32),  LAT/32 };
        p.d[2] = { Wkr,  WkrT,                  DIM, RD,   (DIM/32)*(RD/32),   RD/32  };
        p.d[3] = { Wqr,  WqrT,                  LAT, 1024, (LAT/32)*(1024/32), 1024/32 };
        p.d[4] = { Wvu,  WvuT,                  LAT, DIM,  (LAT/32)*(DIM/32),  DIM/32 };
        p.d[5] = { Wqu,  WquT,                  LAT, DIM,  (LAT/32)*(DIM/32),  DIM/32 };
        p.n = 6;
        int tot = 0;
        for (int i = 0; i < p.n; ++i) tot += p.d[i].tiles;
        if (flat) {
            p.d[6] = { Wo, WoT, DIM, DIM, (DIM/32)*(DIM/32), DIM/32 };
            p.n = 7; tot += p.d[6].tiles;
        }
        phaseA<<<ap.cblocks + tot, blk, 0, stream>>>(ap);
    }

    // Phase B (64-wide tiles -> 544 blocks, DB=1): xw = xb@WxT^T | kr (rope)
    {
        GPack gp;
        gp.g[0] = { xb, WxT,  xw, DIM, DIM, DIM, 1024, 1024/64, T_SEQ/64, 1,
                    0, 0, 0, (1024/64)*(T_SEQ/64), 0, 1024, 0 };
        gp.g[1] = { xb, WkrT, kr, DIM, DIM, DIM, RD,   1,       T_SEQ/64, 1,
                    0, 0, 0, T_SEQ/64, 1 /*rope*/, RD, 0 };
        gp.n = 2;
        gemm_group<64, 1><<<gp.g[0].tiles + gp.g[1].tiles, blk, 0, stream>>>(gp);
    }

    // Phase C/D per chunk: {q, qr(+rope)} group -> q~ (z=16, K=128) ->
    // attention -> U-projection
    for (int c = 0; c < NCH; ++c) {
        const int t0 = c * TCH;
        bf16* q  = flat ? qB  + (size_t)t0 * 2048 : qB;
        bf16* qt = flat ? qtC + (size_t)t0 * 8192 : qtC;
        bf16* qr = flat ? qrC + (size_t)t0 * 1024 : qrC;
        bf16* U  = flat ? uC  + (size_t)t0 * 8192 : uC;
        const bf16* xwc = xw + (size_t)t0 * 1024;

        {   // C1 (64-wide tiles, 768 blocks @ TCH=2048, DB=1): q | qr(+rope)
            GPack gp;
            gp.g[0] = { xwc, WquT, q,  LAT, 1024, LAT, 2048, 2048/64, TCH/128, 1,
                        0, 0, 0, (2048/64)*(TCH/128), 0, 2048, 0 };
            gp.g[1] = { xwc, WqrT, qr, LAT, 1024, LAT, 1024, 1024/64, TCH/128, 1,
                        0, 0, 0, (1024/64)*(TCH/128), 1 /*rope*/, 1024, t0 };
            gp.n = 2;
            gemm_group<128, 1><<<gp.g[0].tiles + gp.g[1].tiles, blk, 0, stream>>>(gp);
        }
        {
            GPack gp;  // q~_h = q_h @ Wku_h^T : M=TCH, N=512, K=128, z=16
            gp.g[0] = { q, Wkub, qt, 128, 2048, 2048, 8192, 512/128, TCH/128, NH,
                        128, 128, 512, (512/128)*(TCH/128)*NH, 0, 512, 0 };
            gp.n = 1;
            gemm128<0><<<gp.g[0].tiles, blk, 0, stream>>>(gp);
        }
        attn_mla<<<TCH, blk, 0, stream>>>(qt, qr, xw, kr, topk, U, t0);
        {   // U-proj (64-wide tiles, 512 blocks @ TCH=2048, DB=1)
            GPack gp;
            gp.g[0] = { U, WvuT, o + (size_t)t0 * DIM, LAT, 8192, LAT, DIM,
                        2, TCH/128, NH, 512, (long)128*LAT, 128,
                        2*(TCH/128)*NH, 0, 128, 0 };
            gp.n = 1;
            gemm_group<128, 1><<<gp.g[0].tiles, blk, 0, stream>>>(gp);
        }
    }

    // Phase E (r22): single launch, out = o @ WoT^T (fp32), 64-wide tiles ->
    // 512 blocks (2/CU) + DB=1.
    {
        if (!flat) {
            TPack p;
            p.d[0] = { Wo, WoT, DIM, DIM, (DIM/32)*(DIM/32), DIM/32 };
            p.n = 1;
            transpose_batch<<<p.d[0].tiles, blk, 0, stream>>>(p);
        }
        GPack gp;
        gp.g[0] = { o, WoT, (bf16*)out, DIM, DIM, DIM, DIM,
                    DIM/64, T_SEQ/128, 1, 0, 0, 0,
                    (DIM/64)*(T_SEQ/128), 4 /*fp32*/, DIM, 0 };
        gp.n = 1;
        gemm_group<128, 1><<<gp.g[0].tiles, blk, 0, stream>>>(gp);
    }
}

// Round 14
// 228.832 us; speedup vs baseline: 1.0159x; 1.0159x over previous
//
#include <hip/hip_runtime.h>
#include <hip/hip_bf16.h>
#include <math.h>

typedef __hip_bfloat16 bf16;
typedef __attribute__((ext_vector_type(4))) float f32x4;
typedef __attribute__((ext_vector_type(8))) short s16x8;

#define T_SEQ 2048
#define DIM   2048
#define NH    16
#define LAT   512
#define RD    64
#define TOPK  32

typedef const __attribute__((address_space(1))) void* gas_ptr;
typedef __attribute__((address_space(3))) void* las_ptr;

// ---------------------------------------------------------------------------
// Grouped GEMM descriptors.
// flags: 1 = RoPE epilogue (rotate col pairs (c, c+32), position = t0+row),
//        2 = column guard (col < N; B-staging rows clamped to N-1),
//        4 = fp32 output (C reinterpreted float*).
// ---------------------------------------------------------------------------
struct GGroup {
    const bf16* A; const bf16* BT; bf16* C;
    int K, lda, ldb, ldc;
    int tx, ty, nz;          // tiles in n, m, z
    long aZ, bZ, cZ;         // element strides per z
    int tiles;               // tx*ty*nz
    int flags, N, t0;
};
struct GPack { GGroup g[4]; int n; };

// ---------------------------------------------------------------------------
// MT x 64-tile grouped GEMM, BK=64. Grid policy (r16/r17 PMC): grid >= 2
// blocks/CU dominates all other levers. DB=1 (r20): 2-phase dbuf.
// r22: with grid >= 2/CU, single-K + DB beats split-K + reduce.
// ---------------------------------------------------------------------------
template<int MT, int DB>
__global__ __launch_bounds__(256)
void gemm_group(GPack gp)
{
    constexpr int MI = MT / 64;          // i-frags per wave (1 or 2)

    int b = blockIdx.x;
    int gi = 0;
    while (gi < gp.n - 1 && b >= gp.g[gi].tiles) { b -= gp.g[gi].tiles; ++gi; }
    const GGroup g = gp.g[gi];

    // T1: bijective XCD swizzle (m204).
    {
        const int nwg = g.tiles;
        const int xcd = b & 7, idx = b >> 3;
        const int qq = nwg >> 3, rr = nwg & 7;
        b = (xcd < rr ? xcd * (qq + 1) : rr * (qq + 1) + (xcd - rr) * qq) + idx;
    }

    const int per_z = g.tx * g.ty;
    const int z   = b / per_z;
    const int rem = b - z * per_z;
    const int bx  = rem % g.tx;
    const int by  = rem / g.tx;

    const bf16* A  = g.A  + (size_t)z * g.aZ;
    const bf16* BT = g.BT + (size_t)z * g.bZ;
    bf16*       C  = g.C  + (size_t)z * g.cZ;

    __shared__ bf16 aL[(DB + 1) * MT * 64];
    __shared__ bf16 bL[(DB + 1) * 64 * 64];

    const int tid  = threadIdx.x;
    const int wave = tid >> 6;
    const int lane = tid & 63;
    const int quad = lane >> 4;
    const int l16  = lane & 15;

    const int tile_m = by * MT;
    const int tile_n = bx * 64;
    const int wrow = wave * (MT / 4);

    const int lrow = lane >> 3;
    const int lke  = (((lane & 7) ^ lrow) * 8);      // XOR-swizzled seg
    const int sw   = l16 & 7;

    f32x4 acc[MI][4] = {};

    const int nt = g.K >> 6;

    auto stage = [&](int t, int sb) {
        const int k0 = t << 6;
#pragma unroll
        for (int p = 0; p < 2 * MI; ++p) {
            const int R = (wave * 2 * MI + p) * 8;
            const bf16* src = A + (size_t)(tile_m + R + lrow) * g.lda + k0 + lke;
            __builtin_amdgcn_global_load_lds((gas_ptr)src,
                (las_ptr)(aL + sb * MT * 64 + R * 64), 16, 0, 0);
        }
#pragma unroll
        for (int p = 0; p < 2; ++p) {
            const int R = (wave * 2 + p) * 8;
            int brow = tile_n + R + lrow;
            if (g.flags & 2) brow = brow < g.N ? brow : g.N - 1;
            const bf16* src = BT + (size_t)brow * g.ldb + k0 + lke;
            __builtin_amdgcn_global_load_lds((gas_ptr)src,
                (las_ptr)(bL + sb * 4096 + R * 64), 16, 0, 0);
        }
    };

    auto compute = [&](int sb) {
#pragma unroll
        for (int ks = 0; ks < 2; ++ks) {
            s16x8 af[MI], bfr[4];
#pragma unroll
            for (int i = 0; i < MI; ++i)
                af[i] = *(const s16x8*)(&aL[sb * MT * 64 + (wrow + i * 16 + l16) * 64 +
                                            (((ks * 4 + quad) ^ sw) * 8)]);
#pragma unroll
            for (int j = 0; j < 4; ++j)
                bfr[j] = *(const s16x8*)(&bL[sb * 4096 + (j * 16 + l16) * 64 +
                                             (((ks * 4 + quad) ^ sw) * 8)]);

#pragma unroll
            for (int i = 0; i < MI; ++i)
#pragma unroll
                for (int j = 0; j < 4; ++j)
                    acc[i][j] = __builtin_amdgcn_mfma_f32_16x16x32_bf16(
                        af[i], bfr[j], acc[i][j], 0, 0, 0);
        }
    };

    if (DB) {
        stage(0, 0);
        asm volatile("s_waitcnt vmcnt(0)" ::: "memory");
        __builtin_amdgcn_s_barrier();
        int cur = 0;
        for (int t = 0; t < nt; ++t) {
            if (t + 1 < nt) stage(t + 1, cur ^ 1);   // loads fly under compute
            compute(cur);
            asm volatile("s_waitcnt vmcnt(0)" ::: "memory");
            __builtin_amdgcn_s_barrier();
            cur ^= 1;
        }
    } else {
        for (int t = 0; t < nt; ++t) {
            stage(t, 0);
            __syncthreads();
            compute(0);
            __syncthreads();
        }
    }

    // D mapping: col = lane&15, row = (lane>>4)*4 + reg   [m89-verified]
    if (g.flags & 1) {
#pragma unroll
        for (int jp = 0; jp < 2; ++jp) {
            const int colL = tile_n + jp * 16 + l16;
            if ((g.flags & 2) && colL >= g.N) continue;
            const float fr = powf(10000.f, -(float)(jp * 16 + l16) / 32.f);
#pragma unroll
            for (int i = 0; i < MI; ++i) {
#pragma unroll
                for (int r = 0; r < 4; ++r) {
                    const int row = tile_m + wrow + i * 16 + quad * 4 + r;
                    float sv, cv;
                    sincosf((float)(g.t0 + row) * fr, &sv, &cv);
                    const float x0 = acc[i][jp][r];
                    const float x1 = acc[i][jp + 2][r];
                    C[(size_t)row * g.ldc + colL]      = __float2bfloat16(x0 * cv - x1 * sv);
                    C[(size_t)row * g.ldc + colL + 32] = __float2bfloat16(x1 * cv + x0 * sv);
                }
            }
        }
    } else if (g.flags & 4) {
        float* Cf = (float*)C;
#pragma unroll
        for (int j = 0; j < 4; ++j) {
            const int col = tile_n + j * 16 + l16;
#pragma unroll
            for (int i = 0; i < MI; ++i)
#pragma unroll
                for (int r = 0; r < 4; ++r) {
                    const int row = tile_m + wrow + i * 16 + quad * 4 + r;
                    Cf[(size_t)row * g.ldc + col] = acc[i][j][r];
                }
        }
    } else {
#pragma unroll
        for (int j = 0; j < 4; ++j) {
            const int col = tile_n + j * 16 + l16;
            if ((g.flags & 2) && col >= g.N) continue;
#pragma unroll
            for (int i = 0; i < MI; ++i)
#pragma unroll
                for (int r = 0; r < 4; ++r) {
                    const int row = tile_m + wrow + i * 16 + quad * 4 + r;
                    C[(size_t)row * g.ldc + col] = __float2bfloat16(acc[i][j][r]);
                }
        }
    }
}

// ---------------------------------------------------------------------------
// 128x128-tile grouped GEMM: 4 waves 2x2, 64x64/wave, acc[4][4].
// DB=1: same 2-phase dbuf. Use when grid >= 2/CU.
// ---------------------------------------------------------------------------
template<int DB>
__global__ __launch_bounds__(256)
void gemm128(GPack gp)
{
    int b = blockIdx.x;
    int gi = 0;
    while (gi < gp.n - 1 && b >= gp.g[gi].tiles) { b -= gp.g[gi].tiles; ++gi; }
    const GGroup g = gp.g[gi];

    {
        const int nwg = g.tiles;
        const int xcd = b & 7, idx = b >> 3;
        const int qq = nwg >> 3, rr = nwg & 7;
        b = (xcd < rr ? xcd * (qq + 1) : rr * (qq + 1) + (xcd - rr) * qq) + idx;
    }

    const int per_z = g.tx * g.ty;
    const int z   = b / per_z;
    const int rem = b - z * per_z;
    const int bx  = rem % g.tx;
    const int by  = rem / g.tx;

    const bf16* A  = g.A  + (size_t)z * g.aZ;
    const bf16* BT = g.BT + (size_t)z * g.bZ;
    bf16*       C  = g.C  + (size_t)z * g.cZ;

    __shared__ bf16 aL[(DB + 1) * 128 * 64];
    __shared__ bf16 bL[(DB + 1) * 128 * 64];

    const int tid  = threadIdx.x;
    const int wave = tid >> 6;
    const int lane = tid & 63;
    const int quad = lane >> 4;
    const int l16  = lane & 15;

    const int tile_m = by * 128;
    const int tile_n = bx * 128;
    const int wm = (wave >> 1) * 64;
    const int wn = (wave & 1) * 64;

    const int lrow = lane >> 3;
    const int lke  = (((lane & 7) ^ lrow) * 8);
    const int sw   = l16 & 7;

    f32x4 acc[4][4] = {};

    const int nt = g.K >> 6;

    auto stage = [&](int t, int sb) {
        const int k0 = t << 6;
#pragma unroll
        for (int p = 0; p < 4; ++p) {
            const int R = (wave * 4 + p) * 8;
            const bf16* srcA = A + (size_t)(tile_m + R + lrow) * g.lda + k0 + lke;
            __builtin_amdgcn_global_load_lds((gas_ptr)srcA,
                (las_ptr)(aL + sb * 8192 + R * 64), 16, 0, 0);
            int brow = tile_n + R + lrow;
            if (g.flags & 2) brow = brow < g.N ? brow : g.N - 1;
            const bf16* srcB = BT + (size_t)brow * g.ldb + k0 + lke;
            __builtin_amdgcn_global_load_lds((gas_ptr)srcB,
                (las_ptr)(bL + sb * 8192 + R * 64), 16, 0, 0);
        }
    };

    auto compute = [&](int sb) {
#pragma unroll
        for (int ks = 0; ks < 2; ++ks) {
            const int seg = ((ks * 4 + quad) ^ sw) * 8;
            s16x8 af[4], bf_[4];
#pragma unroll
            for (int i = 0; i < 4; ++i)
                af[i] = *(const s16x8*)(&aL[sb * 8192 + (wm + i * 16 + l16) * 64 + seg]);
#pragma unroll
            for (int j = 0; j < 4; ++j)
                bf_[j] = *(const s16x8*)(&bL[sb * 8192 + (wn + j * 16 + l16) * 64 + seg]);

#pragma unroll
            for (int i = 0; i < 4; ++i)
#pragma unroll
                for (int j = 0; j < 4; ++j)
                    acc[i][j] = __builtin_amdgcn_mfma_f32_16x16x32_bf16(
                        af[i], bf_[j], acc[i][j], 0, 0, 0);
        }
    };

    if (DB) {
        stage(0, 0);
        asm volatile("s_waitcnt vmcnt(0)" ::: "memory");
        __builtin_amdgcn_s_barrier();
        int cur = 0;
        for (int t = 0; t < nt; ++t) {
            if (t + 1 < nt) stage(t + 1, cur ^ 1);
            compute(cur);
            asm volatile("s_waitcnt vmcnt(0)" ::: "memory");
            __builtin_amdgcn_s_barrier();
            cur ^= 1;
        }
    } else {
        for (int t = 0; t < nt; ++t) {
            stage(t, 0);
            __syncthreads();
            compute(0);
            __syncthreads();
        }
    }

    if (g.flags & 1) {
#pragma unroll
        for (int jp = 0; jp < 2; ++jp) {
            const int colL = tile_n + wn + jp * 16 + l16;
            if ((g.flags & 2) && colL >= g.N) continue;
            const float fr = powf(10000.f, -(float)(jp * 16 + l16) / 32.f);
#pragma unroll
            for (int i = 0; i < 4; ++i) {
#pragma unroll
                for (int r = 0; r < 4; ++r) {
                    const int row = tile_m + wm + i * 16 + quad * 4 + r;
                    float sv, cv;
                    sincosf((float)(g.t0 + row) * fr, &sv, &cv);
                    const float x0 = acc[i][jp][r];
                    const float x1 = acc[i][jp + 2][r];
                    C[(size_t)row * g.ldc + colL]      = __float2bfloat16(x0 * cv - x1 * sv);
                    C[(size_t)row * g.ldc + colL + 32] = __float2bfloat16(x1 * cv + x0 * sv);
                }
            }
        }
    } else if (g.flags & 4) {
        float* Cf = (float*)C;
#pragma unroll
        for (int j = 0; j < 4; ++j) {
            const int col = tile_n + wn + j * 16 + l16;
#pragma unroll
            for (int i = 0; i < 4; ++i)
#pragma unroll
                for (int r = 0; r < 4; ++r) {
                    const int row = tile_m + wm + i * 16 + quad * 4 + r;
                    Cf[(size_t)row * g.ldc + col] = acc[i][j][r];
                }
        }
    } else {
#pragma unroll
        for (int j = 0; j < 4; ++j) {
            const int col = tile_n + wn + j * 16 + l16;
            if ((g.flags & 2) && col >= g.N) continue;
#pragma unroll
            for (int i = 0; i < 4; ++i)
#pragma unroll
                for (int r = 0; r < 4; ++r) {
                    const int row = tile_m + wm + i * 16 + quad * 4 + r;
                    C[(size_t)row * g.ldc + col] = __float2bfloat16(acc[i][j][r]);
                }
        }
    }
}

// ---------------------------------------------------------------------------
// Batched transpose+convert: fp32 (R x C) -> bf16 (C x R), 32x32 LDS tiles.
// ---------------------------------------------------------------------------
struct TDesc { const float* src; bf16* dst; int R; int C; int tiles; int ctiles; };
struct TPack { TDesc d[8]; int n; };

__global__ __launch_bounds__(256)
void transpose_batch(TPack p)
{
    int b = blockIdx.x;
    int mi = 0;
    while (mi < p.n - 1 && b >= p.d[mi].tiles) { b -= p.d[mi].tiles; ++mi; }
    const TDesc d = p.d[mi];
    const int tr = b / d.ctiles, tc = b % d.ctiles;
    const int r0 = tr * 32, c0 = tc * 32;

    __shared__ float lds[32][33];
    const int tx = threadIdx.x & 31, ty = threadIdx.x >> 5;
#pragma unroll
    for (int i = 0; i < 4; ++i)
        lds[ty * 4 + i][tx] = d.src[(size_t)(r0 + ty * 4 + i) * d.C + c0 + tx];
    __syncthreads();
#pragma unroll
    for (int i = 0; i < 4; ++i)
        d.dst[(size_t)(c0 + ty * 4 + i) * d.R + r0 + tx] =
            __float2bfloat16(lds[tx][ty * 4 + i]);
}

// ---------------------------------------------------------------------------
// r21: fused Phase A — converts (block range [0, cblocks)) + transposes
// (rest). One launch instead of two (launch count is first-order).
// ---------------------------------------------------------------------------
struct APack {
    const float* s0; bf16* d0; int n0;
    const float* s1; bf16* d1; int n1;
    int cblocks;
    TPack tp;
};

__global__ __launch_bounds__(256)
void phaseA(APack p)
{
    __shared__ float lds[32][33];
    if ((int)blockIdx.x < p.cblocks) {
        int i = blockIdx.x * blockDim.x + threadIdx.x;   // 8-elem units
        const float* s; bf16* d;
        if (i < p.n0) { s = p.s0; d = p.d0; }
        else if (i < p.n0 + p.n1) { i -= p.n0; s = p.s1; d = p.d1; }
        else return;
        const float4 a = *(const float4*)(s + (size_t)i * 8);
        const float4 b = *(const float4*)(s + (size_t)i * 8 + 4);
        bf16 t[8];
        t[0] = __float2bfloat16(a.x); t[1] = __float2bfloat16(a.y);
        t[2] = __float2bfloat16(a.z); t[3] = __float2bfloat16(a.w);
        t[4] = __float2bfloat16(b.x); t[5] = __float2bfloat16(b.y);
        t[6] = __float2bfloat16(b.z); t[7] = __float2bfloat16(b.w);
        *(uint4*)(d + (size_t)i * 8) = *(uint4*)t;
        return;
    }
    int b = blockIdx.x - p.cblocks;
    int mi = 0;
    while (mi < p.tp.n - 1 && b >= p.tp.d[mi].tiles) { b -= p.tp.d[mi].tiles; ++mi; }
    const TDesc d = p.tp.d[mi];
    const int tr = b / d.ctiles, tc = b % d.ctiles;
    const int r0 = tr * 32, c0 = tc * 32;
    const int tx = threadIdx.x & 31, ty = threadIdx.x >> 5;
#pragma unroll
    for (int i = 0; i < 4; ++i)
        lds[ty * 4 + i][tx] = d.src[(size_t)(r0 + ty * 4 + i) * d.C + c0 + tx];
    __syncthreads();
#pragma unroll
    for (int i = 0; i < 4; ++i)
        d.dst[(size_t)(c0 + ty * 4 + i) * d.R + r0 + tx] =
            __float2bfloat16(lds[tx][ty * 4 + i]);
}

// ---------------------------------------------------------------------------
// MLA-absorbed sparse attention. One block per query t.
// r17: QK^T wave-K-split + cross-wave LDS reduction.
// r21: ckv quad-XOR seg swizzle (global-side stage permute, readers un-XOR).
// r24: r23's LDS-staged U store REVERTED (regressed +2.6us: the extra
// 2 barriers + 16KB LDS round-trip cost more than coalescing saved — L2
// already write-combines the sequential 32B sectors). Scalar store kept.
// r24: T5 s_setprio(1) around QK^T and PV MFMA clusters — attn is the
// m191-favorable regime (independent blocks, waves at different phases);
// NOT applied to the barrier-lockstep GEMMs (m190 null).
// ---------------------------------------------------------------------------
__global__ __launch_bounds__(256)
void attn_mla(const bf16* __restrict__ qt,   // [rows][8192] chunk (q~ per head)
              const bf16* __restrict__ qr,   // [rows][1024] chunk (rope'd)
              const bf16* __restrict__ xw,   // [2048][1024], ckv = cols 512..1023
              const bf16* __restrict__ kr,   // [2048][64] (rope'd)
              const int*  __restrict__ topk, // [2048][32]
              bf16* __restrict__ U,          // [rows][8192]
              int t0)
{
    __shared__ short ckv_s[32 * 520];
    __shared__ short kr_s[32 * 72];
    __shared__ short qr_s[16 * 72];
    __shared__ short P_s[4][16 * 40];
    __shared__ float red[4][64][4];
    __shared__ int   idx_s[32];

    const int tl   = blockIdx.x;
    const int tg   = t0 + tl;
    const int tid  = threadIdx.x;
    const int wv   = tid >> 6;
    const int lane = tid & 63;
    const int quad = lane >> 4;
    const int l16  = lane & 15;

    if (tid < 32) {
        int j = topk[(size_t)tg * TOPK + tid];
        idx_s[tid] = (j < 0 || j >= T_SEQ) ? 0 : j;
    }
    __syncthreads();

    // Stage ckv rows with seg-XOR on the GLOBAL side (dest linear):
    // LDS[row][seg s] = global seg (s ^ (row>>3)); row>>3 == wv here.
#pragma unroll
    for (int i = 0; i < 8; ++i) {
        const int row = wv * 8 + i;
        const int j = idx_s[row];
        __builtin_amdgcn_global_load_lds(
            (gas_ptr)(xw + (size_t)j * 1024 + 512 + ((lane ^ wv) * 8)),
            (las_ptr)(ckv_s + row * 520), 16, 0, 0);
    }
    {
        const int row = tid >> 3, seg = tid & 7;
        const int j = idx_s[row];
        *(uint4*)(kr_s + row * 72 + seg * 8) =
            *(const uint4*)(kr + (size_t)j * RD + seg * 8);
    }
    if (tid < 128) {
        const int head = tid >> 3, seg = tid & 7;
        *(uint4*)(qr_s + head * 72 + seg * 8) =
            *(const uint4*)(qr + (size_t)tl * 1024 + head * 64 + seg * 8);
    }
    __syncthreads();

    // QK^T partials: wave wv covers qt K-slices 4wv..4wv+3 (of 16).
    const bf16* qrow = qt + (size_t)tl * 8192 + l16 * 512;
    const int h0 = l16 >> 3;             // swz(row = l16); row 16+l16 -> 2+h0
    f32x4 sc[2] = {};
    __builtin_amdgcn_s_setprio(1);
#pragma unroll
    for (int kk = 0; kk < 4; ++kk) {
        const int ks = wv * 4 + kk;
        s16x8 a  = *(const s16x8*)(qrow + ks * 32 + quad * 8);
        s16x8 b0 = *(const s16x8*)(ckv_s + l16 * 520 +
                                   (((ks * 4 + quad) ^ h0) * 8));
        s16x8 b1 = *(const s16x8*)(ckv_s + (16 + l16) * 520 +
                                   (((ks * 4 + quad) ^ (2 + h0)) * 8));
        sc[0] = __builtin_amdgcn_mfma_f32_16x16x32_bf16(a, b0, sc[0], 0, 0, 0);
        sc[1] = __builtin_amdgcn_mfma_f32_16x16x32_bf16(a, b1, sc[1], 0, 0, 0);
    }
    if (wv < 2) {   // rope contribution: K=64 -> 2 slices, one per wave 0/1
        const int ks = wv;
        s16x8 a  = *(const s16x8*)(qr_s + l16 * 72 + ks * 32 + quad * 8);
        s16x8 b0 = *(const s16x8*)(kr_s + l16 * 72 + ks * 32 + quad * 8);
        s16x8 b1 = *(const s16x8*)(kr_s + (16 + l16) * 72 + ks * 32 + quad * 8);
        sc[0] = __builtin_amdgcn_mfma_f32_16x16x32_bf16(a, b0, sc[0], 0, 0, 0);
        sc[1] = __builtin_amdgcn_mfma_f32_16x16x32_bf16(a, b1, sc[1], 0, 0, 0);
    }
    __builtin_amdgcn_s_setprio(0);

    // Cross-wave reduction (2 passes through 4KB LDS).
    *(f32x4*)red[wv][lane] = sc[0];
    __syncthreads();
    sc[0] = *(const f32x4*)red[0][lane] + *(const f32x4*)red[1][lane] +
            *(const f32x4*)red[2][lane] + *(const f32x4*)red[3][lane];
    __syncthreads();
    *(f32x4*)red[wv][lane] = sc[1];
    __syncthreads();
    sc[1] = *(const f32x4*)red[0][lane] + *(const f32x4*)red[1][lane] +
            *(const f32x4*)red[2][lane] + *(const f32x4*)red[3][lane];

    const float scale = 0.0721687836487032f;   // 1/sqrt(192)
    float inv[4];
    short* pw = P_s[wv];
#pragma unroll
    for (int r = 0; r < 4; ++r) {
        float s0 = sc[0][r] * scale, s1 = sc[1][r] * scale;
        float mx = fmaxf(s0, s1);
#pragma unroll
        for (int off = 1; off < 16; off <<= 1) mx = fmaxf(mx, __shfl_xor(mx, off));
        float p0 = __expf(s0 - mx), p1 = __expf(s1 - mx);
        float l = p0 + p1;
#pragma unroll
        for (int off = 1; off < 16; off <<= 1) l += __shfl_xor(l, off);
        inv[r] = 1.f / l;
        pw[(quad * 4 + r) * 40 + l16]      = __builtin_bit_cast(short, __float2bfloat16(p0));
        pw[(quad * 4 + r) * 40 + 16 + l16] = __builtin_bit_cast(short, __float2bfloat16(p1));
    }

    s16x8 ap = *(const s16x8*)(pw + l16 * 40 + quad * 8);
    __builtin_amdgcn_s_setprio(1);
#pragma unroll
    for (int tt = 0; tt < 8; ++tt) {
        const int n0 = wv * 128 + tt * 16;
        const int cs = (n0 >> 3) + h0;          // global col seg of n0+l16
        s16x8 b;
#pragma unroll
        for (int j = 0; j < 8; ++j)
            b[j] = ckv_s[(quad * 8 + j) * 520 + ((cs ^ quad) << 3) + (l16 & 7)];
        f32x4 u = {};
        u = __builtin_amdgcn_mfma_f32_16x16x32_bf16(ap, b, u, 0, 0, 0);
#pragma unroll
        for (int r = 0; r < 4; ++r)
            U[(size_t)tl * 8192 + (quad * 4 + r) * 512 + n0 + l16] =
                __float2bfloat16(u[r] * inv[r]);
    }
    __builtin_amdgcn_s_setprio(0);
}

// ---------------------------------------------------------------------------
extern "C" void kernel_launch(void* const* d_in, const int* in_sizes, int n_in,
                              void* d_out, int out_size, void* d_ws, size_t ws_size,
                              hipStream_t stream)
{
    const float* x    = (const float*)d_in[0];
    const float* Wqd  = (const float*)d_in[1];
    const float* Wqu  = (const float*)d_in[2];
    const float* Wqr  = (const float*)d_in[3];
    const float* Wkvd = (const float*)d_in[4];
    const float* Wku  = (const float*)d_in[5];
    const float* Wvu  = (const float*)d_in[6];
    const float* Wkr  = (const float*)d_in[7];
    const float* Wo   = (const float*)d_in[8];
    const int*   topk = (const int*)d_in[9];
    float* out = (float*)d_out;

    const size_t KB = 1024;
    char* ws = (char*)d_ws;
    const bool flat = ws_size >= (size_t)128000 * KB;
    const int  TCH  = flat ? 2048 : 512;
    const int  NCH  = T_SEQ / TCH;

    // q~ factorization (r10): q = ql@Wqu (ref-exact), q~_h = q_h@Wku_h^T
    // (rank-128 bottleneck) -> 8.6 GF vs 17.2+1.1 GF for the Wcomb path.
    size_t oXB, oWxT, oWkrT, oWquT, oWkub, oWqrT, oWvuT, oQ, oXW, oKR,
           oQR, oO, oWoT, oQT, oU;
    if (flat) {
        oXB = 0;       oWxT = 8192;   oWkrT = 12288; oWquT = 12544;
        oWkub = 14592; oWqrT = 16640; oWvuT = 17664; oQ = 19712;
        oXW = 27904;   oKR = 32000;   oQR = 32256;   oO = 36352;
        oWoT = 44544;  oQT = 52736;   oU = 85504;
    } else {
        // chunked (TCH=512), 38.3 MB peak; xb/WxT/WkrT die after phase B,
        // q aliases into dead-xb region, WoT over dead qt at the end.
        oXW = 0;       oKR = 4096;    oWquT = 4352;  oWkub = 6400;
        oWqrT = 8448;  oWvuT = 9472;  oO = 11520;    oXB = 19712;
        oWxT = 27904;  oWkrT = 32000; oQ = 19712;    oQT = 21760;
        oQR = 29952;   oU = 30976;    oWoT = 21760;
    }
    bf16* xb   = (bf16*)(ws + oXB * KB);
    bf16* WxT  = (bf16*)(ws + oWxT * KB);
    bf16* WkrT = (bf16*)(ws + oWkrT * KB);
    bf16* WquT = (bf16*)(ws + oWquT * KB);
    bf16* Wkub = (bf16*)(ws + oWkub * KB);
    bf16* WqrT = (bf16*)(ws + oWqrT * KB);
    bf16* WvuT = (bf16*)(ws + oWvuT * KB);
    bf16* qB   = (bf16*)(ws + oQ * KB);
    bf16* xw   = (bf16*)(ws + oXW * KB);
    bf16* kr   = (bf16*)(ws + oKR * KB);
    bf16* qrC  = (bf16*)(ws + oQR * KB);
    bf16* o    = (bf16*)(ws + oO * KB);
    bf16* WoT  = (bf16*)(ws + oWoT * KB);
    bf16* qtC  = (bf16*)(ws + oQT * KB);
    bf16* uC   = (bf16*)(ws + oU * KB);

    dim3 blk(256);

    // Phase A: fused convert (x, Wku) + transposes, single launch (r21).
    {
        int n0 = T_SEQ * DIM / 8, n1 = LAT * DIM / 8;
        APack ap;
        ap.s0 = x;   ap.d0 = xb;   ap.n0 = n0;
        ap.s1 = Wku; ap.d1 = Wkub; ap.n1 = n1;
        ap.cblocks = (n0 + n1 + 255) / 256;
        TPack& p = ap.tp;
        p.d[0] = { Wqd,  WxT,                   DIM, LAT,  (DIM/32)*(LAT/32),  LAT/32 };
        p.d[1] = { Wkvd, WxT + (size_t)LAT*DIM, DIM, LAT,  (DIM/32)*(LAT/32),  LAT/32 };
        p.d[2] = { Wkr,  WkrT,                  DIM, RD,   (DIM/32)*(RD/32),   RD/32  };
        p.d[3] = { Wqr,  WqrT,                  LAT, 1024, (LAT/32)*(1024/32), 1024/32 };
        p.d[4] = { Wvu,  WvuT,                  LAT, DIM,  (LAT/32)*(DIM/32),  DIM/32 };
        p.d[5] = { Wqu,  WquT,                  LAT, DIM,  (LAT/32)*(DIM/32),  DIM/32 };
        p.n = 6;
        int tot = 0;
        for (int i = 0; i < p.n; ++i) tot += p.d[i].tiles;
        if (flat) {
            p.d[6] = { Wo, WoT, DIM, DIM, (DIM/32)*(DIM/32), DIM/32 };
            p.n = 7; tot += p.d[6].tiles;
        }
        phaseA<<<ap.cblocks + tot, blk, 0, stream>>>(ap);
    }

    // Phase B (64-wide tiles -> 544 blocks, DB=1): xw = xb@WxT^T | kr (rope)
    {
        GPack gp;
        gp.g[0] = { xb, WxT,  xw, DIM, DIM, DIM, 1024, 1024/64, T_SEQ/64, 1,
                    0, 0, 0, (1024/64)*(T_SEQ/64), 0, 1024, 0 };
        gp.g[1] = { xb, WkrT, kr, DIM, DIM, DIM, RD,   1,       T_SEQ/64, 1,
                    0, 0, 0, T_SEQ/64, 1 /*rope*/, RD, 0 };
        gp.n = 2;
        gemm_group<64, 1><<<gp.g[0].tiles + gp.g[1].tiles, blk, 0, stream>>>(gp);
    }

    // Phase C/D per chunk: {q, qr(+rope)} group -> q~ (z=16, K=128) ->
    // attention -> U-projection
    for (int c = 0; c < NCH; ++c) {
        const int t0 = c * TCH;
        bf16* q  = flat ? qB  + (size_t)t0 * 2048 : qB;
        bf16* qt = flat ? qtC + (size_t)t0 * 8192 : qtC;
        bf16* qr = flat ? qrC + (size_t)t0 * 1024 : qrC;
        bf16* U  = flat ? uC  + (size_t)t0 * 8192 : uC;
        const bf16* xwc = xw + (size_t)t0 * 1024;

        {   // C1 (64-wide tiles, 768 blocks @ TCH=2048, DB=1): q | qr(+rope)
            GPack gp;
            gp.g[0] = { xwc, WquT, q,  LAT, 1024, LAT, 2048, 2048/64, TCH/128, 1,
                        0, 0, 0, (2048/64)*(TCH/128), 0, 2048, 0 };
            gp.g[1] = { xwc, WqrT, qr, LAT, 1024, LAT, 1024, 1024/64, TCH/128, 1,
                        0, 0, 0, (1024/64)*(TCH/128), 1 /*rope*/, 1024, t0 };
            gp.n = 2;
            gemm_group<128, 1><<<gp.g[0].tiles + gp.g[1].tiles, blk, 0, stream>>>(gp);
        }
        {
            GPack gp;  // q~_h = q_h @ Wku_h^T : M=TCH, N=512, K=128, z=16
            gp.g[0] = { q, Wkub, qt, 128, 2048, 2048, 8192, 512/128, TCH/128, NH,
                        128, 128, 512, (512/128)*(TCH/128)*NH, 0, 512, 0 };
            gp.n = 1;
            gemm128<0><<<gp.g[0].tiles, blk, 0, stream>>>(gp);
        }
        attn_mla<<<TCH, blk, 0, stream>>>(qt, qr, xw, kr, topk, U, t0);
        {   // U-proj (64-wide tiles, 512 blocks @ TCH=2048, DB=1)
            GPack gp;
            gp.g[0] = { U, WvuT, o + (size_t)t0 * DIM, LAT, 8192, LAT, DIM,
                        2, TCH/128, NH, 512, (long)128*LAT, 128,
                        2*(TCH/128)*NH, 0, 128, 0 };
            gp.n = 1;
            gemm_group<128, 1><<<gp.g[0].tiles, blk, 0, stream>>>(gp);
        }
    }

    // Phase E (r22): single launch, out = o @ WoT^T (fp32), 64-wide tiles ->
    // 512 blocks (2/CU) + DB=1.
    {
        if (!flat) {
            TPack p;
            p.d[0] = { Wo, WoT, DIM, DIM, (DIM/32)*(DIM/32), DIM/32 };
            p.n = 1;
            transpose_batch<<<p.d[0].tiles, blk, 0, stream>>>(p);
        }
        GPack gp;
        gp.g[0] = { o, WoT, (bf16*)out, DIM, DIM, DIM, DIM,
                    DIM/64, T_SEQ/128, 1, 0, 0, 0,
                    (DIM/64)*(T_SEQ/128), 4 /*fp32*/, DIM, 0 };
        gp.n = 1;
        gemm_group<128, 1><<<gp.g[0].tiles, blk, 0, stream>>>(gp);
    }
}